// Round 1
// baseline (346.590 us; speedup 1.0000x reference)
//
#include <hip/hip_runtime.h>
#include <hip/hip_bf16.h>

// Problem constants (B,S,H,E) = (64,1024,256,256)
#define S_LEN 1024
#define B_DIM 64
#define H_DIM 256
#define E_DIM 256
#define M_ROWS (B_DIM * S_LEN)   // 65536 rows
#define NCHUNK 16
#define CHUNK 64                  // S_LEN / NCHUNK

typedef __attribute__((ext_vector_type(8))) short bf16x8;
typedef __attribute__((ext_vector_type(4))) float f32x4;

// Load 8 consecutive f32 (32B-aligned) and convert to bf16 (RNE)
__device__ __forceinline__ bf16x8 cvt8(const float* __restrict__ p) {
  const float4* p4 = reinterpret_cast<const float4*>(p);
  float4 x = p4[0], y = p4[1];
  float f[8] = {x.x, x.y, x.z, x.w, y.x, y.y, y.z, y.w};
  bf16x8 r;
#pragma unroll
  for (int j = 0; j < 8; ++j) {
    union { float ff; unsigned u; } t;
    t.ff = f[j];
    unsigned u = t.u;
    r[j] = (short)((u + 0x7fffu + ((u >> 16) & 1u)) >> 16);
  }
  return r;
}

// Kernel 1: w[b,s] = exp(dot(alpha[b,s,:], Wa) + ba) * mask[b,s]
// One wave per row; lane l handles 4 contiguous floats (float4).
__global__ __launch_bounds__(256) void w_kernel(
    const float* __restrict__ alpha, const float* __restrict__ Wa,
    const float* __restrict__ ba, const float* __restrict__ mask,
    float* __restrict__ wv) {
  int wave = threadIdx.x >> 6, lane = threadIdx.x & 63;
  long long row = (long long)blockIdx.x * 4 + wave;
  const float4 a = reinterpret_cast<const float4*>(alpha + row * H_DIM)[lane];
  const float4 wa = reinterpret_cast<const float4*>(Wa)[lane];
  float d = a.x * wa.x + a.y * wa.y + a.z * wa.z + a.w * wa.w;
#pragma unroll
  for (int m = 32; m; m >>= 1) d += __shfl_xor(d, m);
  if (lane == 0) wv[row] = expf(d + ba[0]) * mask[row];
}

// Kernel 2: invacc[b,i] = 1 / (suffix_sum_{j>=i} w[b,j] + 1e-10)
// One block per b, 1024 threads, double-buffered Hillis-Steele reverse scan.
__global__ __launch_bounds__(1024) void acc_kernel(
    const float* __restrict__ wv, float* __restrict__ invacc) {
  __shared__ float s[2][S_LEN];
  int b = blockIdx.x, i = threadIdx.x;
  s[0][i] = wv[b * S_LEN + i];
  __syncthreads();
  int src = 0;
#pragma unroll
  for (int off = 1; off < S_LEN; off <<= 1) {
    float v = s[src][i];
    if (i + off < S_LEN) v += s[src][i + off];
    s[src ^ 1][i] = v;
    __syncthreads();
    src ^= 1;
  }
  invacc[b * S_LEN + i] = 1.0f / (s[src][i] + 1e-10f);
}

// Kernel 3: P[r,e] = w[r] * tanh(beta[r,:]·Wb[e,:] + bb[e]) * embed[r,e]
// bf16 MFMA GEMM: block = 64 rows x 256 cols, 4 waves (each 64x64 tile).
// Epilogue additionally produces chunk column sums Psum[chunk, e]
// (block's 64 rows == exactly one (b, chunk)).
__global__ __launch_bounds__(256) void gemm_kernel(
    const float* __restrict__ beta, const float* __restrict__ Wb,
    const float* __restrict__ bb, const float* __restrict__ embed,
    const float* __restrict__ wv, float* __restrict__ P,
    float* __restrict__ Psum) {
  const int K = H_DIM;
  int wave = threadIdx.x >> 6, lane = threadIdx.x & 63;
  long long rowbase = (long long)blockIdx.x * 64;
  int colbase = wave * 64;
  int rl = lane & 15, kg = lane >> 4;

  f32x4 acc[4][4] = {};
#pragma unroll
  for (int k0 = 0; k0 < K; k0 += 32) {
    int kf = k0 + kg * 8;
    bf16x8 am[4], bn[4];
#pragma unroll
    for (int i = 0; i < 4; ++i)
      am[i] = cvt8(beta + (rowbase + i * 16 + rl) * K + kf);
#pragma unroll
    for (int j = 0; j < 4; ++j)
      bn[j] = cvt8(Wb + (long long)(colbase + j * 16 + rl) * K + kf);
#pragma unroll
    for (int i = 0; i < 4; ++i)
#pragma unroll
      for (int j = 0; j < 4; ++j)
        acc[i][j] = __builtin_amdgcn_mfma_f32_16x16x32_bf16(am[i], bn[j],
                                                            acc[i][j], 0, 0, 0);
  }

  // Epilogue. D mapping: col = lane&15, row = (lane>>4)*4 + reg  [m89/m91]
#pragma unroll
  for (int j = 0; j < 4; ++j) {
    int e = colbase + j * 16 + rl;
    float bbe = bb[e];
    float colsum = 0.f;
#pragma unroll
    for (int i = 0; i < 4; ++i) {
#pragma unroll
      for (int q = 0; q < 4; ++q) {
        long long r = rowbase + i * 16 + kg * 4 + q;
        float val = tanhf(acc[i][j][q] + bbe);
        float p = wv[r] * val * embed[r * E_DIM + e];
        P[r * E_DIM + e] = p;
        colsum += p;
      }
    }
    colsum += __shfl_xor(colsum, 16);
    colsum += __shfl_xor(colsum, 32);
    if (kg == 0) Psum[(long long)blockIdx.x * E_DIM + e] = colsum;
  }
}

// Kernel 4: suffix scan within chunk + cross-chunk offset; out = T * invacc
// One block per (b, chunk); thread t owns column e=t.
__global__ __launch_bounds__(256) void scan_kernel(
    const float* __restrict__ P, const float* __restrict__ Psum,
    const float* __restrict__ invacc, float* __restrict__ out) {
  int blk = blockIdx.x;
  int b = blk >> 4, c = blk & (NCHUNK - 1);
  int e = threadIdx.x;
  float off = 0.f;
  for (int c2 = c + 1; c2 < NCHUNK; ++c2)
    off += Psum[(long long)(b * NCHUNK + c2) * E_DIM + e];

  long long base = ((long long)b * S_LEN + c * CHUNK) * E_DIM + e;
  const float* Pb = P + base;
  float* Ob = out + base;
  const float* ia = invacc + b * S_LEN + c * CHUNK;

  float running = off;
#pragma unroll
  for (int bb0 = CHUNK - 16; bb0 >= 0; bb0 -= 16) {
    float v[16];
#pragma unroll
    for (int t = 0; t < 16; ++t) v[t] = Pb[(long long)(bb0 + t) * E_DIM];
#pragma unroll
    for (int t = 15; t >= 0; --t) {
      running += v[t];
      Ob[(long long)(bb0 + t) * E_DIM] = running * ia[bb0 + t];
    }
  }
}

extern "C" void kernel_launch(void* const* d_in, const int* in_sizes, int n_in,
                              void* d_out, int out_size, void* d_ws,
                              size_t ws_size, hipStream_t stream) {
  const float* alpha = (const float*)d_in[0];  // [B,S,H]
  const float* beta = (const float*)d_in[1];   // [B,S,H]
  const float* embed = (const float*)d_in[2];  // [B,S,E]
  const float* mask = (const float*)d_in[3];   // [B,S]
  const float* Wb = (const float*)d_in[4];     // [E,H]
  const float* bb = (const float*)d_in[5];     // [E]
  const float* Wa = (const float*)d_in[6];     // [H]
  const float* ba = (const float*)d_in[7];     // [1]
  float* out = (float*)d_out;                  // [B,S,E]

  // Workspace layout (floats): w[65536] | invacc[65536] | Psum[1024*256] | P[M*E]
  float* wv = (float*)d_ws;
  float* invacc = wv + M_ROWS;
  float* Psum = invacc + M_ROWS;
  float* P = Psum + (M_ROWS / CHUNK) * E_DIM;

  w_kernel<<<M_ROWS / 4, 256, 0, stream>>>(alpha, Wa, ba, mask, wv);
  acc_kernel<<<B_DIM, 1024, 0, stream>>>(wv, invacc);
  gemm_kernel<<<M_ROWS / 64, 256, 0, stream>>>(beta, Wb, bb, embed, wv, P, Psum);
  scan_kernel<<<M_ROWS / CHUNK, 256, 0, stream>>>(P, Psum, invacc, out);
}

// Round 2
// 283.076 us; speedup vs baseline: 1.2244x; 1.2244x over previous
//
#include <hip/hip_runtime.h>
#include <hip/hip_bf16.h>

// Problem constants (B,S,H,E) = (64,1024,256,256)
#define S_LEN 1024
#define B_DIM 64
#define H_DIM 256
#define E_DIM 256
#define M_ROWS (B_DIM * S_LEN)   // 65536 rows

#define CT_COLS 64                 // output cols per block
#define NCT (E_DIM / CT_COLS)      // 4 col-tiles
#define CHUNK_R 256                // rows per chunk
#define NCHUNKS (S_LEN / CHUNK_R)  // 4
#define NTHREADS 1024
#define NWAVES 16

#define BPAD 264                   // Bsm row stride (bf16 elems): 256 + 8 pad
#define PPAD 66                    // Psm row stride (f32): 64 + 2 pad

typedef __attribute__((ext_vector_type(8))) short bf16x8;
typedef __attribute__((ext_vector_type(4))) float f32x4;

__device__ __forceinline__ short cvt1(float f) {
  union { float ff; unsigned u; } t;
  t.ff = f;
  unsigned u = t.u;
  return (short)((u + 0x7fffu + ((u >> 16) & 1u)) >> 16);  // RNE
}

__device__ __forceinline__ bf16x8 cvt8v(float4 x, float4 y) {
  bf16x8 r;
  r[0] = cvt1(x.x); r[1] = cvt1(x.y); r[2] = cvt1(x.z); r[3] = cvt1(x.w);
  r[4] = cvt1(y.x); r[5] = cvt1(y.y); r[6] = cvt1(y.z); r[7] = cvt1(y.w);
  return r;
}

// Kernel 1: w[b,s] = exp(dot(alpha[b,s,:], Wa) + ba) * mask[b,s]
__global__ __launch_bounds__(256) void w_kernel(
    const float* __restrict__ alpha, const float* __restrict__ Wa,
    const float* __restrict__ ba, const float* __restrict__ mask,
    float* __restrict__ wv) {
  int wave = threadIdx.x >> 6, lane = threadIdx.x & 63;
  long long row = (long long)blockIdx.x * 4 + wave;
  const float4 a = reinterpret_cast<const float4*>(alpha + row * H_DIM)[lane];
  const float4 wa = reinterpret_cast<const float4*>(Wa)[lane];
  float d = a.x * wa.x + a.y * wa.y + a.z * wa.z + a.w * wa.w;
#pragma unroll
  for (int m = 32; m; m >>= 1) d += __shfl_xor(d, m);
  if (lane == 0) wv[row] = expf(d + ba[0]) * mask[row];
}

// Kernel 2: invacc[b,i] = 1 / (suffix_sum_{j>=i} w[b,j] + 1e-10)
__global__ __launch_bounds__(1024) void acc_kernel(
    const float* __restrict__ wv, float* __restrict__ invacc) {
  __shared__ float s[2][S_LEN];
  int b = blockIdx.x, i = threadIdx.x;
  s[0][i] = wv[b * S_LEN + i];
  __syncthreads();
  int src = 0;
#pragma unroll
  for (int off = 1; off < S_LEN; off <<= 1) {
    float v = s[src][i];
    if (i + off < S_LEN) v += s[src][i + off];
    s[src ^ 1][i] = v;
    __syncthreads();
    src ^= 1;
  }
  invacc[b * S_LEN + i] = 1.0f / (s[src][i] + 1e-10f);
}

// Kernel 3 (fused): per block = (batch b, 64-col tile).
// GEMM P = w*tanh(beta@Wb^T+bb)*embed  computed chunk-by-chunk (256 rows),
// suffix-scanned in LDS with a per-column carry, out written directly.
// P / Psum never touch HBM.
__global__ __launch_bounds__(NTHREADS, 1) void fused_kernel(
    const float* __restrict__ beta, const float* __restrict__ Wb,
    const float* __restrict__ bb, const float* __restrict__ embed,
    const float* __restrict__ wv, const float* __restrict__ invacc,
    float* __restrict__ out) {
  __shared__ short Bsm[CT_COLS * BPAD];        // 33 KB  bf16 Wb col-tile
  __shared__ float Psm[CHUNK_R * PPAD];        // 66 KB  P chunk tile
  __shared__ float segsum[NWAVES * CT_COLS];   // 4 KB
  __shared__ float carry[CT_COLS];             // suffix carry per col

  const int tid = threadIdx.x;
  const int b = blockIdx.x >> 2;               // NCT = 4
  const int colbase = (blockIdx.x & 3) * CT_COLS;

  // ---- stage Wb col-tile -> bf16 LDS (once; reused by all chunks/k-steps)
  {
    int c = tid >> 4, ks = (tid & 15) * 16;
    const float4* src =
        reinterpret_cast<const float4*>(Wb + (long long)(colbase + c) * H_DIM + ks);
    float4 v0 = src[0], v1 = src[1], v2 = src[2], v3 = src[3];
    *reinterpret_cast<bf16x8*>(&Bsm[c * BPAD + ks]) = cvt8v(v0, v1);
    *reinterpret_cast<bf16x8*>(&Bsm[c * BPAD + ks + 8]) = cvt8v(v2, v3);
  }
  if (tid < CT_COLS) carry[tid] = 0.f;
  __syncthreads();

  const int wave = tid >> 6, lane = tid & 63;
  const int rl = lane & 15, kg = lane >> 4;
  const int col = tid & 63, seg = tid >> 6;    // scan mapping (seg == wave)

  for (int chunk = NCHUNKS - 1; chunk >= 0; --chunk) {
    const long long rowstart = (long long)b * S_LEN + chunk * CHUNK_R;
    const long long arow = rowstart + wave * 16 + rl;
    const float* aptr = beta + arow * H_DIM + kg * 8;

    f32x4 acc[4] = {{0.f,0.f,0.f,0.f},{0.f,0.f,0.f,0.f},
                    {0.f,0.f,0.f,0.f},{0.f,0.f,0.f,0.f}};

    // depth-2 software pipeline on A (f32 global -> reg -> bf16)
    float4 a0[2], a1[2];
    a0[0] = *reinterpret_cast<const float4*>(aptr + 0);
    a1[0] = *reinterpret_cast<const float4*>(aptr + 4);
    a0[1] = *reinterpret_cast<const float4*>(aptr + 32);
    a1[1] = *reinterpret_cast<const float4*>(aptr + 36);
#pragma unroll
    for (int ks = 0; ks < 8; ++ks) {
      float4 na0 = {0.f,0.f,0.f,0.f}, na1 = {0.f,0.f,0.f,0.f};
      if (ks < 6) {
        na0 = *reinterpret_cast<const float4*>(aptr + (ks + 2) * 32);
        na1 = *reinterpret_cast<const float4*>(aptr + (ks + 2) * 32 + 4);
      }
      bf16x8 am = cvt8v(a0[0], a1[0]);
      int kb = ks * 32 + kg * 8;
#pragma unroll
      for (int j = 0; j < 4; ++j) {
        bf16x8 bn = *reinterpret_cast<const bf16x8*>(&Bsm[(j * 16 + rl) * BPAD + kb]);
        acc[j] = __builtin_amdgcn_mfma_f32_16x16x32_bf16(am, bn, acc[j], 0, 0, 0);
      }
      a0[0] = a0[1]; a1[0] = a1[1];
      a0[1] = na0;   a1[1] = na1;
    }

    // ---- epilogue: p = w * tanh(acc + bb) * embed  -> Psm
    // D frag mapping: col = j*16 + rl, row-in-16 = kg*4 + q  [m89/m91]
#pragma unroll
    for (int q = 0; q < 4; ++q) {
      int rloc = wave * 16 + kg * 4 + q;
      long long r = rowstart + rloc;
      float wvv = wv[r];
      const float* erow = embed + r * E_DIM + colbase;
#pragma unroll
      for (int j = 0; j < 4; ++j) {
        int c = j * 16 + rl;
        float p = wvv * tanhf(acc[j][q] + bb[colbase + c]) * erow[c];
        Psm[rloc * PPAD + c] = p;
      }
    }
    __syncthreads();

    // ---- scan: 64 cols x 16 segs of 16 rows, suffix order
    float lsum = 0.f;
#pragma unroll
    for (int i = 0; i < 16; ++i)
      lsum += Psm[(seg * 16 + i) * PPAD + col];
    segsum[seg * CT_COLS + col] = lsum;
    __syncthreads();

    float offset = carry[col];
    for (int s2 = seg + 1; s2 < NWAVES; ++s2)
      offset += segsum[s2 * CT_COLS + col];
    __syncthreads();                       // all carry reads done
    if (seg == 0) carry[col] = offset + lsum;

    float running = offset;
    long long rbase = rowstart + seg * 16;
#pragma unroll
    for (int i = 15; i >= 0; --i) {
      running += Psm[(seg * 16 + i) * PPAD + col];
      out[(rbase + i) * E_DIM + colbase + col] = running * invacc[rbase + i];
    }
    __syncthreads();                       // Psm/carry safe for next chunk
  }
}

extern "C" void kernel_launch(void* const* d_in, const int* in_sizes, int n_in,
                              void* d_out, int out_size, void* d_ws,
                              size_t ws_size, hipStream_t stream) {
  const float* alpha = (const float*)d_in[0];  // [B,S,H]
  const float* beta = (const float*)d_in[1];   // [B,S,H]
  const float* embed = (const float*)d_in[2];  // [B,S,E]
  const float* mask = (const float*)d_in[3];   // [B,S]
  const float* Wb = (const float*)d_in[4];     // [E,H]
  const float* bb = (const float*)d_in[5];     // [E]
  const float* Wa = (const float*)d_in[6];     // [H]
  const float* ba = (const float*)d_in[7];     // [1]
  float* out = (float*)d_out;                  // [B,S,E]

  // Workspace: wv[65536] | invacc[65536]
  float* wv = (float*)d_ws;
  float* invacc = wv + M_ROWS;

  w_kernel<<<M_ROWS / 4, 256, 0, stream>>>(alpha, Wa, ba, mask, wv);
  acc_kernel<<<B_DIM, 1024, 0, stream>>>(wv, invacc);
  fused_kernel<<<B_DIM * NCT, NTHREADS, 0, stream>>>(beta, Wb, bb, embed, wv,
                                                     invacc, out);
}

// Round 3
// 259.504 us; speedup vs baseline: 1.3356x; 1.0908x over previous
//
#include <hip/hip_runtime.h>
#include <hip/hip_bf16.h>

// Problem constants (B,S,H,E) = (64,1024,256,256)
#define S_LEN 1024
#define B_DIM 64
#define H_DIM 256
#define E_DIM 256
#define M_ROWS (B_DIM * S_LEN)   // 65536 rows

#define CT_COLS 64                 // output cols per block
#define NCT (E_DIM / CT_COLS)      // 4 col-tiles
#define CHUNK_R 256                // rows per chunk
#define NCHUNKS (S_LEN / CHUNK_R)  // 4
#define NTHREADS 1024
#define NWAVES 16

#define BPAD 264                   // Bsm row stride (bf16 elems): 256 + 8 pad

typedef __attribute__((ext_vector_type(8))) short bf16x8;
typedef __attribute__((ext_vector_type(4))) float f32x4;

__device__ __forceinline__ short cvt1(float f) {
  union { float ff; unsigned u; } t;
  t.ff = f;
  unsigned u = t.u;
  return (short)((u + 0x7fffu + ((u >> 16) & 1u)) >> 16);  // RNE
}

__device__ __forceinline__ bf16x8 cvt8v(float4 x, float4 y) {
  bf16x8 r;
  r[0] = cvt1(x.x); r[1] = cvt1(x.y); r[2] = cvt1(x.z); r[3] = cvt1(x.w);
  r[4] = cvt1(y.x); r[5] = cvt1(y.y); r[6] = cvt1(y.z); r[7] = cvt1(y.w);
  return r;
}

// fast tanh: 1 - 2/(e^{2x}+1); rcp accurate to ~1 ulp, fine vs 6.4e-2 threshold
__device__ __forceinline__ float fast_tanh(float x) {
  float t = __expf(2.0f * x);
  return 1.0f - 2.0f * __builtin_amdgcn_rcpf(t + 1.0f);
}

// Kernel 1: w[b,s] = exp(dot(alpha[b,s,:], Wa) + ba) * mask[b,s]
__global__ __launch_bounds__(256) void w_kernel(
    const float* __restrict__ alpha, const float* __restrict__ Wa,
    const float* __restrict__ ba, const float* __restrict__ mask,
    float* __restrict__ wv) {
  int wave = threadIdx.x >> 6, lane = threadIdx.x & 63;
  long long row = (long long)blockIdx.x * 4 + wave;
  const float4 a = reinterpret_cast<const float4*>(alpha + row * H_DIM)[lane];
  const float4 wa = reinterpret_cast<const float4*>(Wa)[lane];
  float d = a.x * wa.x + a.y * wa.y + a.z * wa.z + a.w * wa.w;
#pragma unroll
  for (int m = 32; m; m >>= 1) d += __shfl_xor(d, m);
  if (lane == 0) wv[row] = expf(d + ba[0]) * mask[row];
}

// Kernel 2: invacc[b,i] = 1 / (suffix_sum_{j>=i} w[b,j] + 1e-10)
__global__ __launch_bounds__(1024) void acc_kernel(
    const float* __restrict__ wv, float* __restrict__ invacc) {
  __shared__ float s[2][S_LEN];
  int b = blockIdx.x, i = threadIdx.x;
  s[0][i] = wv[b * S_LEN + i];
  __syncthreads();
  int src = 0;
#pragma unroll
  for (int off = 1; off < S_LEN; off <<= 1) {
    float v = s[src][i];
    if (i + off < S_LEN) v += s[src][i + off];
    s[src ^ 1][i] = v;
    __syncthreads();
    src ^= 1;
  }
  invacc[b * S_LEN + i] = 1.0f / (s[src][i] + 1e-10f);
}

// Kernel 3 (fused): block = (batch b, 64-col tile), XCD-swizzled so all 4
// col-tiles of a batch share one XCD's L2 (beta fetched once per XCD).
// GEMM chunk (256 rows) -> epilogue in fragment regs -> in-register suffix
// scan (q-chain + shfl_xor across kg + 4KB segsum LDS across waves + carry).
// Only 38 KB LDS -> 2 blocks/CU (8 waves/SIMD).
__global__ __launch_bounds__(NTHREADS, 8) void fused_kernel(
    const float* __restrict__ beta, const float* __restrict__ Wb,
    const float* __restrict__ bb, const float* __restrict__ embed,
    const float* __restrict__ wv, const float* __restrict__ invacc,
    float* __restrict__ out) {
  __shared__ short Bsm[CT_COLS * BPAD];        // 33 KB bf16 Wb col-tile
  __shared__ float segsum[NWAVES * CT_COLS];   // 4 KB per-wave col totals
  __shared__ float carry[CT_COLS];             // cross-chunk suffix carry

  const int tid = threadIdx.x;
  // XCD-aware remap: XCD = hw%8 (round-robin dispatch). All 4 ct of a given
  // b land on the same XCD. Bijective over 256 blocks.
  const int hw = blockIdx.x;
  const int b = (hw & 7) + (((hw >> 3) & 7) << 3);
  const int colbase = (hw >> 6) * CT_COLS;

  // ---- stage Wb col-tile -> bf16 LDS (once; reused by all chunks/k-steps)
  {
    int c = tid >> 4, ks = (tid & 15) * 16;
    const float4* src =
        reinterpret_cast<const float4*>(Wb + (long long)(colbase + c) * H_DIM + ks);
    float4 v0 = src[0], v1 = src[1], v2 = src[2], v3 = src[3];
    *reinterpret_cast<bf16x8*>(&Bsm[c * BPAD + ks]) = cvt8v(v0, v1);
    *reinterpret_cast<bf16x8*>(&Bsm[c * BPAD + ks + 8]) = cvt8v(v2, v3);
  }
  if (tid < CT_COLS) carry[tid] = 0.f;
  __syncthreads();

  const int wave = tid >> 6, lane = tid & 63;
  const int rl = lane & 15, kg = lane >> 4;

  for (int chunk = NCHUNKS - 1; chunk >= 0; --chunk) {
    const long long rowstart = (long long)b * S_LEN + chunk * CHUNK_R;
    const long long r0 = rowstart + wave * 16;          // wave's 16-row group
    const float* aptr = beta + (r0 + rl) * H_DIM + kg * 8;

    f32x4 acc[4] = {{0.f,0.f,0.f,0.f},{0.f,0.f,0.f,0.f},
                    {0.f,0.f,0.f,0.f},{0.f,0.f,0.f,0.f}};

    // depth-2 software pipeline on A (f32 global -> reg -> bf16)
    float4 a0[2], a1[2];
    a0[0] = *reinterpret_cast<const float4*>(aptr + 0);
    a1[0] = *reinterpret_cast<const float4*>(aptr + 4);
    a0[1] = *reinterpret_cast<const float4*>(aptr + 32);
    a1[1] = *reinterpret_cast<const float4*>(aptr + 36);
#pragma unroll
    for (int ks = 0; ks < 8; ++ks) {
      float4 na0 = {0.f,0.f,0.f,0.f}, na1 = {0.f,0.f,0.f,0.f};
      if (ks < 6) {
        na0 = *reinterpret_cast<const float4*>(aptr + (ks + 2) * 32);
        na1 = *reinterpret_cast<const float4*>(aptr + (ks + 2) * 32 + 4);
      }
      bf16x8 am = cvt8v(a0[0], a1[0]);
      int kb = ks * 32 + kg * 8;
#pragma unroll
      for (int j = 0; j < 4; ++j) {
        bf16x8 bn = *reinterpret_cast<const bf16x8*>(&Bsm[(j * 16 + rl) * BPAD + kb]);
        acc[j] = __builtin_amdgcn_mfma_f32_16x16x32_bf16(am, bn, acc[j], 0, 0, 0);
      }
      a0[0] = a0[1]; a1[0] = a1[1];
      a0[1] = na0;   a1[1] = na1;
    }

    // ---- epilogue + in-register suffix scan
    // D frag: col = j*16 + rl, row-in-16 = kg*4 + q  [m89/m91]
    float wvq[4], inv[4];
#pragma unroll
    for (int q = 0; q < 4; ++q) {
      long long r = r0 + kg * 4 + q;
      wvq[q] = wv[r];
      inv[q] = invacc[r];
    }

    float sv[4][4];   // suffix chains: sv[j][q] = sum_{q'>=q} p[j][q']
    float off[4];     // cross-kg (+later cross-wave +carry) offset
    float cn[4];      // new carry (valid on wave0,kg0 lanes)
#pragma unroll
    for (int j = 0; j < 4; ++j) {
      int c = j * 16 + rl;
      int e = colbase + c;
      float bbe = bb[e];
      float p[4];
#pragma unroll
      for (int q = 0; q < 4; ++q) {
        long long r = r0 + kg * 4 + q;
        p[q] = wvq[q] * fast_tanh(acc[j][q] + bbe) * embed[r * E_DIM + e];
      }
      sv[j][3] = p[3];
      sv[j][2] = p[2] + sv[j][3];
      sv[j][1] = p[1] + sv[j][2];
      sv[j][0] = p[0] + sv[j][1];
      float gtot = sv[j][0];
      float t16 = __shfl_xor(gtot, 16);
      float t32 = __shfl_xor(gtot, 32);
      float t48 = __shfl_xor(gtot, 48);
      off[j] = (kg == 0) ? (t16 + t32 + t48)
             : (kg == 1) ? (t32 + t48)
             : (kg == 2) ? t16 : 0.f;
      float wtot = gtot + t16 + t32 + t48;
      if (kg == 0) segsum[wave * CT_COLS + c] = wtot;
    }
    __syncthreads();  // (A) segsum visible

#pragma unroll
    for (int j = 0; j < 4; ++j) {
      int c = j * 16 + rl;
      float segoff = carry[c];
      for (int w2 = wave + 1; w2 < NWAVES; ++w2)
        segoff += segsum[w2 * CT_COLS + c];
      off[j] += segoff;
      cn[j] = off[j] + sv[j][0];  // for wave0/kg0: old carry + this chunk total
#pragma unroll
      for (int q = 0; q < 4; ++q) {
        long long r = r0 + kg * 4 + q;
        out[r * E_DIM + colbase + c] = (sv[j][q] + off[j]) * inv[q];
      }
    }
    __syncthreads();  // (B) all carry/segsum reads done
    if (wave == 0 && kg == 0) {
#pragma unroll
      for (int j = 0; j < 4; ++j) carry[j * 16 + rl] = cn[j];
    }
  }
}

extern "C" void kernel_launch(void* const* d_in, const int* in_sizes, int n_in,
                              void* d_out, int out_size, void* d_ws,
                              size_t ws_size, hipStream_t stream) {
  const float* alpha = (const float*)d_in[0];  // [B,S,H]
  const float* beta = (const float*)d_in[1];   // [B,S,H]
  const float* embed = (const float*)d_in[2];  // [B,S,E]
  const float* mask = (const float*)d_in[3];   // [B,S]
  const float* Wb = (const float*)d_in[4];     // [E,H]
  const float* bb = (const float*)d_in[5];     // [E]
  const float* Wa = (const float*)d_in[6];     // [H]
  const float* ba = (const float*)d_in[7];     // [1]
  float* out = (float*)d_out;                  // [B,S,E]

  // Workspace: wv[65536] | invacc[65536]
  float* wv = (float*)d_ws;
  float* invacc = wv + M_ROWS;

  w_kernel<<<M_ROWS / 4, 256, 0, stream>>>(alpha, Wa, ba, mask, wv);
  acc_kernel<<<B_DIM, 1024, 0, stream>>>(wv, invacc);
  fused_kernel<<<B_DIM * NCT, NTHREADS, 0, stream>>>(beta, Wb, bb, embed, wv,
                                                     invacc, out);
}

// Round 4
// 242.934 us; speedup vs baseline: 1.4267x; 1.0682x over previous
//
#include <hip/hip_runtime.h>
#include <hip/hip_bf16.h>

// Problem constants (B,S,H,E) = (64,1024,256,256)
#define S_LEN 1024
#define B_DIM 64
#define H_DIM 256
#define E_DIM 256
#define M_ROWS (B_DIM * S_LEN)   // 65536 rows

#define CT_COLS 64                 // output cols per block
#define NCT (E_DIM / CT_COLS)      // 4 col-tiles
#define CHUNK_R 256                // rows per chunk
#define NCHUNKS (S_LEN / CHUNK_R)  // 4
#define NTHREADS 1024
#define NWAVES 16

#define BPAD 264                   // Bsm row stride (bf16 elems): 256 + 8 pad

typedef __attribute__((ext_vector_type(8))) short bf16x8;
typedef __attribute__((ext_vector_type(4))) float f32x4;

__device__ __forceinline__ short cvt1(float f) {
  union { float ff; unsigned u; } t;
  t.ff = f;
  unsigned u = t.u;
  return (short)((u + 0x7fffu + ((u >> 16) & 1u)) >> 16);  // RNE
}

__device__ __forceinline__ bf16x8 cvt8v(float4 x, float4 y) {
  bf16x8 r;
  r[0] = cvt1(x.x); r[1] = cvt1(x.y); r[2] = cvt1(x.z); r[3] = cvt1(x.w);
  r[4] = cvt1(y.x); r[5] = cvt1(y.y); r[6] = cvt1(y.z); r[7] = cvt1(y.w);
  return r;
}

// fast tanh: 1 - 2/(e^{2x}+1)
__device__ __forceinline__ float fast_tanh(float x) {
  float t = __expf(2.0f * x);
  return 1.0f - 2.0f * __builtin_amdgcn_rcpf(t + 1.0f);
}

// Kernel 1: w[b,s] = exp(dot(alpha[b,s,:], Wa) + ba) * mask[b,s]
__global__ __launch_bounds__(256) void w_kernel(
    const float* __restrict__ alpha, const float* __restrict__ Wa,
    const float* __restrict__ ba, const float* __restrict__ mask,
    float* __restrict__ wv) {
  int wave = threadIdx.x >> 6, lane = threadIdx.x & 63;
  long long row = (long long)blockIdx.x * 4 + wave;
  const float4 a = reinterpret_cast<const float4*>(alpha + row * H_DIM)[lane];
  const float4 wa = reinterpret_cast<const float4*>(Wa)[lane];
  float d = a.x * wa.x + a.y * wa.y + a.z * wa.z + a.w * wa.w;
#pragma unroll
  for (int m = 32; m; m >>= 1) d += __shfl_xor(d, m);
  if (lane == 0) wv[row] = expf(d + ba[0]) * mask[row];
}

// Kernel 2: invacc[b,i] = 1 / (suffix_sum_{j>=i} w[b,j] + 1e-10)
__global__ __launch_bounds__(1024) void acc_kernel(
    const float* __restrict__ wv, float* __restrict__ invacc) {
  __shared__ float s[2][S_LEN];
  int b = blockIdx.x, i = threadIdx.x;
  s[0][i] = wv[b * S_LEN + i];
  __syncthreads();
  int src = 0;
#pragma unroll
  for (int off = 1; off < S_LEN; off <<= 1) {
    float v = s[src][i];
    if (i + off < S_LEN) v += s[src][i + off];
    s[src ^ 1][i] = v;
    __syncthreads();
    src ^= 1;
  }
  invacc[b * S_LEN + i] = 1.0f / (s[src][i] + 1e-10f);
}

// Kernel 3 (fused): block = (batch b, 64-col tile), XCD-swizzled.
// Fully software-pipelined across chunks: A depth-2 pipeline rolls over the
// chunk boundary; embed/wv/inv for the next chunk prefetched during the
// current chunk's epilogue+scan. One barrier per chunk (double-buffered
// segsum/carry). __launch_bounds__(1024,4): VGPR cap 128 (grid gives only
// 16 waves/CU, so 4/SIMD is the true occupancy anyway).
__global__ __launch_bounds__(NTHREADS, 4) void fused_kernel(
    const float* __restrict__ beta, const float* __restrict__ Wb,
    const float* __restrict__ bb, const float* __restrict__ embed,
    const float* __restrict__ wv, const float* __restrict__ invacc,
    float* __restrict__ out) {
  __shared__ short Bsm[CT_COLS * BPAD];            // 33 KB bf16 Wb col-tile
  __shared__ float segsum[2][NWAVES * CT_COLS];    // 8 KB (double-buffered)
  __shared__ float carry[2][CT_COLS];              // cross-chunk carry

  const int tid = threadIdx.x;
  // XCD-aware remap: all 4 col-tiles of a batch share one XCD's L2.
  const int hw = blockIdx.x;
  const int b = (hw & 7) + (((hw >> 3) & 7) << 3);
  const int colbase = (hw >> 6) * CT_COLS;

  // ---- stage Wb col-tile -> bf16 LDS (once)
  {
    int c = tid >> 4, ks = (tid & 15) * 16;
    const float4* src =
        reinterpret_cast<const float4*>(Wb + (long long)(colbase + c) * H_DIM + ks);
    float4 v0 = src[0], v1 = src[1], v2 = src[2], v3 = src[3];
    *reinterpret_cast<bf16x8*>(&Bsm[c * BPAD + ks]) = cvt8v(v0, v1);
    *reinterpret_cast<bf16x8*>(&Bsm[c * BPAD + ks + 8]) = cvt8v(v2, v3);
  }
  if (tid < CT_COLS) { carry[0][tid] = 0.f; carry[1][tid] = 0.f; }
  __syncthreads();

  const int wave = tid >> 6, lane = tid & 63;
  const int rl = lane & 15, kg = lane >> 4;

  // bb hoisted out of the chunk loop
  float bbv[4];
#pragma unroll
  for (int j = 0; j < 4; ++j) bbv[j] = bb[colbase + j * 16 + rl];

  // A-pipeline (depth 2, rolls across chunks)
  const float* ap =
      beta + ((long long)b * S_LEN + 3 * CHUNK_R + wave * 16 + rl) * H_DIM + kg * 8;
  float4 pa0 = *reinterpret_cast<const float4*>(ap + 0);
  float4 pa1 = *reinterpret_cast<const float4*>(ap + 4);
  float4 pb0 = *reinterpret_cast<const float4*>(ap + 32);
  float4 pb1 = *reinterpret_cast<const float4*>(ap + 36);

  // chunk-input prefetch (current chunk = 3)
  float emb[4][4], wvq[4], inv[4];
  {
    const long long r0 = (long long)b * S_LEN + 3 * CHUNK_R + wave * 16 + kg * 4;
#pragma unroll
    for (int q = 0; q < 4; ++q) {
      wvq[q] = wv[r0 + q];
      inv[q] = invacc[r0 + q];
#pragma unroll
      for (int j = 0; j < 4; ++j)
        emb[q][j] = embed[(r0 + q) * E_DIM + colbase + j * 16 + rl];
    }
  }

  for (int chunk = NCHUNKS - 1; chunk >= 0; --chunk) {
    const int nc = (chunk > 0) ? chunk - 1 : 0;  // next chunk (clamped)
    const long long rowstart = (long long)b * S_LEN + chunk * CHUNK_R;
    const long long r0 = rowstart + wave * 16;
    const float* ap_next =
        beta + ((long long)b * S_LEN + nc * CHUNK_R + wave * 16 + rl) * H_DIM + kg * 8;

    f32x4 acc[4] = {{0.f,0.f,0.f,0.f},{0.f,0.f,0.f,0.f},
                    {0.f,0.f,0.f,0.f},{0.f,0.f,0.f,0.f}};

#pragma unroll
    for (int ks = 0; ks < 8; ++ks) {
      float4 n0, n1;
      if (ks < 6) {
        n0 = *reinterpret_cast<const float4*>(ap + (ks + 2) * 32);
        n1 = *reinterpret_cast<const float4*>(ap + (ks + 2) * 32 + 4);
      } else {  // roll into next chunk's first two k-tiles
        n0 = *reinterpret_cast<const float4*>(ap_next + (ks - 6) * 32);
        n1 = *reinterpret_cast<const float4*>(ap_next + (ks - 6) * 32 + 4);
      }
      bf16x8 am = cvt8v(pa0, pa1);
      int kb = ks * 32 + kg * 8;
#pragma unroll
      for (int j = 0; j < 4; ++j) {
        bf16x8 bn = *reinterpret_cast<const bf16x8*>(&Bsm[(j * 16 + rl) * BPAD + kb]);
        acc[j] = __builtin_amdgcn_mfma_f32_16x16x32_bf16(am, bn, acc[j], 0, 0, 0);
      }
      pa0 = pb0; pa1 = pb1; pb0 = n0; pb1 = n1;
    }
    ap = ap_next;

    // ---- prefetch next chunk's embed/wv/inv (hides under epilogue+scan)
    float emb_n[4][4], wvq_n[4], inv_n[4];
    {
      const long long rn = (long long)b * S_LEN + nc * CHUNK_R + wave * 16 + kg * 4;
#pragma unroll
      for (int q = 0; q < 4; ++q) {
        wvq_n[q] = wv[rn + q];
        inv_n[q] = invacc[rn + q];
#pragma unroll
        for (int j = 0; j < 4; ++j)
          emb_n[q][j] = embed[(rn + q) * E_DIM + colbase + j * 16 + rl];
      }
    }

    // ---- epilogue + in-register suffix scan
    // D frag: col = j*16 + rl, row-in-16 = kg*4 + q  [m89/m91]
    const int rd = chunk & 1;
    float sv[4][4], off[4];
#pragma unroll
    for (int j = 0; j < 4; ++j) {
      int c = j * 16 + rl;
      float p[4];
#pragma unroll
      for (int q = 0; q < 4; ++q)
        p[q] = wvq[q] * fast_tanh(acc[j][q] + bbv[j]) * emb[q][j];
      sv[j][3] = p[3];
      sv[j][2] = p[2] + sv[j][3];
      sv[j][1] = p[1] + sv[j][2];
      sv[j][0] = p[0] + sv[j][1];
      float gtot = sv[j][0];
      float t16 = __shfl_xor(gtot, 16);
      float t32 = __shfl_xor(gtot, 32);
      float t48 = __shfl_xor(gtot, 48);
      off[j] = (kg == 0) ? (t16 + t32 + t48)
             : (kg == 1) ? (t32 + t48)
             : (kg == 2) ? t16 : 0.f;
      float wtot = gtot + t16 + t32 + t48;
      if (kg == 0) segsum[rd][wave * CT_COLS + c] = wtot;
    }
    __syncthreads();  // segsum[rd] visible; carry[rd] stable

#pragma unroll
    for (int j = 0; j < 4; ++j) {
      int c = j * 16 + rl;
      float segoff = carry[rd][c];
#pragma unroll
      for (int w2 = 0; w2 < NWAVES; ++w2) {
        float t = segsum[rd][w2 * CT_COLS + c];
        segoff += (w2 > wave) ? t : 0.f;
      }
      off[j] += segoff;
      if (wave == 0 && kg == 0) carry[rd ^ 1][c] = off[j] + sv[j][0];
#pragma unroll
      for (int q = 0; q < 4; ++q) {
        long long r = r0 + kg * 4 + q;
        out[r * E_DIM + colbase + c] = (sv[j][q] + off[j]) * inv[q];
      }
    }
    // no trailing barrier: next chunk uses the other segsum/carry buffer

    // rotate prefetched chunk inputs
#pragma unroll
    for (int q = 0; q < 4; ++q) {
      wvq[q] = wvq_n[q]; inv[q] = inv_n[q];
#pragma unroll
      for (int j = 0; j < 4; ++j) emb[q][j] = emb_n[q][j];
    }
  }
}

extern "C" void kernel_launch(void* const* d_in, const int* in_sizes, int n_in,
                              void* d_out, int out_size, void* d_ws,
                              size_t ws_size, hipStream_t stream) {
  const float* alpha = (const float*)d_in[0];  // [B,S,H]
  const float* beta = (const float*)d_in[1];   // [B,S,H]
  const float* embed = (const float*)d_in[2];  // [B,S,E]
  const float* mask = (const float*)d_in[3];   // [B,S]
  const float* Wb = (const float*)d_in[4];     // [E,H]
  const float* bb = (const float*)d_in[5];     // [E]
  const float* Wa = (const float*)d_in[6];     // [H]
  const float* ba = (const float*)d_in[7];     // [1]
  float* out = (float*)d_out;                  // [B,S,E]

  // Workspace: wv[65536] | invacc[65536]
  float* wv = (float*)d_ws;
  float* invacc = wv + M_ROWS;

  w_kernel<<<M_ROWS / 4, 256, 0, stream>>>(alpha, Wa, ba, mask, wv);
  acc_kernel<<<B_DIM, 1024, 0, stream>>>(wv, invacc);
  fused_kernel<<<B_DIM * NCT, NTHREADS, 0, stream>>>(beta, Wb, bb, embed, wv,
                                                     invacc, out);
}